// Round 1
// baseline (351.446 us; speedup 1.0000x reference)
//
#include <hip/hip_runtime.h>

// MaxUnpooling2D: out[b, mask[b,h,w,c]] = updates[b,h,w,c], rest zeros.
// B=16, H=W=64, C=256, OH=OW=128.
// mask is per-batch flat index into [OH*OW*C]. Indices are unique per the
// reference's setup (top-left of each 2x2 window), so plain stores suffice
// (tf.scatter_nd .add into zeros with unique indices == store).

constexpr int B = 16;
constexpr int H = 64, W = 64, C = 256;
constexpr int IN_PER_BATCH  = H * W * C;          // 2^20 = 1,048,576
constexpr int OUT_PER_BATCH = (2 * H) * (2 * W) * C; // 2^22 = 4,194,304
constexpr long long N_IN = (long long)B * IN_PER_BATCH; // 16,777,216

__global__ void unpool_scatter_kernel(const float* __restrict__ updates,
                                      const int* __restrict__ mask,
                                      float* __restrict__ out) {
    long long i = (long long)blockIdx.x * blockDim.x + threadIdx.x;
    if (i >= N_IN) return;
    int b = (int)(i >> 20);                 // i / IN_PER_BATCH
    int m = mask[i];                        // per-batch flat index
    out[(long long)b * OUT_PER_BATCH + m] = updates[i];
}

extern "C" void kernel_launch(void* const* d_in, const int* in_sizes, int n_in,
                              void* d_out, int out_size, void* d_ws, size_t ws_size,
                              hipStream_t stream) {
    const float* updates = (const float*)d_in[0];
    const int*   mask    = (const int*)d_in[1];
    float*       out     = (float*)d_out;

    // Output is re-poisoned to 0xAA before every timed launch — must zero it.
    hipMemsetAsync(out, 0, (size_t)out_size * sizeof(float), stream);

    const int block = 256;
    const int grid  = (int)((N_IN + block - 1) / block); // 65536 blocks
    unpool_scatter_kernel<<<grid, block, 0, stream>>>(updates, mask, out);
}